// Round 6
// baseline (19820.601 us; speedup 1.0000x reference)
//
#include <hip/hip_runtime.h>

// RadialNCA — XLA-f32 bit-replication attempt.
// Gold = shipped jax/XLA float32 trajectory (evidence: f64 pipeline lands
// 3.1e-2 away => gold has its own f32-class rounding; bf16 diverges to 1.0
// => chaotic gain G~3e5; passing needs bit-matching, not accuracy).
// Replicated ops per step:
//   mm1: dot27, ascending-k single-acc FMA (Eigen gebp)  + b1(=0)
//   tanh: XLA/Eigen fast-tanh rational: clamp +/-7.90531110763549805,
//         |x|<0.0004 -> x, fmuladd poly chains, IEEE f32 division
//   mm2: dot256, ascending-k single-acc FMA (+ b2=0)
//   update: 0.5f*delta (exact), + s0 (f32 add), clip via min/max
// State stored f32 each step (same rounding events as gold).

#define BATCH 8
#define HGT 256
#define WID 256
#define NHID 256
#define ALPHA 0.5f

// ws layout (floats): [0, 6291456) state ping buffer; then W1^T (+b1), W2
#define WS_W1T_OFF (BATCH * HGT * WID * 3)
#define WS_W2_OFF  (WS_W1T_OFF + 28 * NHID)

// Exact XLA/Eigen generic_fast_tanh_float
__device__ __forceinline__ float tanh_xla(float x) {
    const float cl = 7.90531110763549805f;
    float xc = fminf(fmaxf(x, -cl), cl);
    float x2 = xc * xc;
    float p = fmaf(x2, -2.76076847742355e-16f, 2.00018790482477e-13f);
    p = fmaf(x2, p, -8.60467152213735e-11f);
    p = fmaf(x2, p, 5.12229709037114e-08f);
    p = fmaf(x2, p, 1.48572235717979e-05f);
    p = fmaf(x2, p, 6.37261928875436e-04f);
    p = fmaf(x2, p, 4.89352455891786e-03f);
    p = xc * p;
    float q = fmaf(x2, 1.19825839466702e-06f, 1.18534705686654e-04f);
    q = fmaf(x2, q, 2.26843463243900e-03f);
    q = fmaf(x2, q, 4.89352518554385e-03f);
    float r = p / q;                       // IEEE f32 div (no fast-math)
    return (fabsf(x) < 0.0004f) ? x : r;
}

// w1t[n][k] = W1[k][n] for k<27; w1t[n][27] = b1[n]; then W2
__global__ __launch_bounds__(256) void nca_prep(const float* __restrict__ W1,
                                                const float* __restrict__ b1,
                                                const float* __restrict__ W2,
                                                float* __restrict__ ws) {
    int n = threadIdx.x;
    float* w1t = ws + WS_W1T_OFF;
#pragma unroll
    for (int k = 0; k < 27; ++k) w1t[n * 28 + k] = W1[k * NHID + n];
    w1t[n * 28 + 27] = b1[n];
    ws[WS_W2_OFF + n] = W2[n];
}

__global__ __launch_bounds__(256) void nca_step(const float* __restrict__ sin,
                                                float* __restrict__ sout,
                                                const float* __restrict__ ws,
                                                const float* __restrict__ b2p) {
    __shared__ float lw1[NHID * 28];
    __shared__ float lw2[NHID];
    const int tid = threadIdx.x;

    const float* w1t = ws + WS_W1T_OFF;
#pragma unroll
    for (int i = 0; i < 28; ++i) lw1[i * 256 + tid] = w1t[i * 256 + tid];
    lw2[tid] = ws[WS_W2_OFF + tid];
    __syncthreads();

    const int gid = blockIdx.x * 256 + tid;   // 0 .. 131071
    const int xq = gid & 63;
    const int y  = (gid >> 6) & 255;
    const int b  = gid >> 14;
    const int x0 = xq * 4;

    // neighborhood rows y-1..y+1, cols x0-1..x0+4, 3 channels
    float X[3][6][3];
#pragma unroll
    for (int r = 0; r < 3; ++r) {
        const int yy = y + r - 1;
        const bool yok = (yy >= 0) && (yy < HGT);
        const float* rowp = sin + (((long)b * HGT + (yok ? yy : 0)) * WID) * 3;
#pragma unroll
        for (int cc = 0; cc < 6; ++cc) {
            const int xx = x0 + cc - 1;
            const bool ok = yok && (xx >= 0) && (xx < WID);
            if (ok) {
                X[r][cc][0] = rowp[xx * 3 + 0];
                X[r][cc][1] = rowp[xx * 3 + 1];
                X[r][cc][2] = rowp[xx * 3 + 2];
            } else {
                X[r][cc][0] = 0.f; X[r][cc][1] = 0.f; X[r][cc][2] = 0.f;
            }
        }
    }

    float delta[4] = {0.f, 0.f, 0.f, 0.f};

    for (int n = 0; n < NHID; ++n) {
        float w[28];
        const float4* wp = (const float4*)&lw1[n * 28];
#pragma unroll
        for (int q = 0; q < 7; ++q) ((float4*)w)[q] = wp[q];
        const float w2n = lw2[n];

#pragma unroll
        for (int p = 0; p < 4; ++p) {
            // mm1: ascending-k single-accumulator FMA from 0 (Eigen gebp),
            // then +b1 (separate add; b1==0 -> no-op bitwise)
            float acc = 0.f;
#pragma unroll
            for (int kh = 0; kh < 3; ++kh)
#pragma unroll
                for (int kw = 0; kw < 3; ++kw)
#pragma unroll
                    for (int c = 0; c < 3; ++c)
                        acc = fmaf(X[kh][kw + p][c], w[(kh * 3 + kw) * 3 + c], acc);
            acc = acc + w[27];                  // + b1[n]
            const float h = tanh_xla(acc);
            delta[p] = fmaf(h, w2n, delta[p]);  // mm2: ascending-n FMA
        }
    }

    const float b2v = b2p[0];
    float* op = sout + (((long)b * HGT + y) * WID + x0) * 3;
#pragma unroll
    for (int p = 0; p < 4; ++p) {
        const float s0 = X[1][p + 1][0];
        const float d  = delta[p] + b2v;        // + b2 (zero)
        const float td = ALPHA * d;             // exact (exponent shift)
        float pat = s0 + td;                    // f32 add
        pat = fminf(fmaxf(pat, 0.f), 1.f);      // clip
        op[p * 3 + 0] = pat;
        op[p * 3 + 1] = X[1][p + 1][1];
        op[p * 3 + 2] = X[1][p + 1][2];
    }
}

extern "C" void kernel_launch(void* const* d_in, const int* in_sizes, int n_in,
                              void* d_out, int out_size, void* d_ws, size_t ws_size,
                              hipStream_t stream) {
    const float* state = (const float*)d_in[0];
    const float* W1    = (const float*)d_in[1];
    const float* b1    = (const float*)d_in[2];
    const float* W2    = (const float*)d_in[3];
    const float* b2    = (const float*)d_in[4];

    float* ws_state = (float*)d_ws;
    float* out      = (float*)d_out;

    nca_prep<<<1, 256, 0, stream>>>(W1, b1, W2, ws_state);

    const int nblocks = (BATCH * HGT * (WID / 4)) / 256;   // 512

    for (int t = 0; t < 128; ++t) {
        const float* in  = (t == 0) ? state : (((t - 1) & 1) ? out : ws_state);
        float*       dst = (t & 1) ? out : ws_state;
        nca_step<<<nblocks, 256, 0, stream>>>(in, dst, ws_state, b2);
    }
}